// Round 10
// baseline (161.251 us; speedup 1.0000x reference)
//
#include <hip/hip_runtime.h>

#define CIN  32
#define OCH  64
#define HH   56
#define WW   56
#define BB   4
#define OT   4                  // output channels per block (R8 config = best, 70.0us)
#define REP  8                  // DIAGNOSTIC: repeat compute-phase 8x, scale by 1/8
#define IMG  (HH * WW)          // 3136
#define NW   18432              // 64*32*3*3
#define PH   58
#define PW   58
#define PIMG (PH * PW)          // 3364 padded image
#define NXPK (BB * (CIN/2) * PIMG)   // 215296 packed x uints
#define XPKBLKS (NXPK / 256)         // 841 (exact)
#define NWPK (OCH * (CIN/2) * 9)     // 9216 packed weight uints
#define WPKBLKS (NWPK / 256)         // 36 (exact)
#define WOFFu 64                     // packed weights at wsu+64 (uint units)
#define XOFFu (WOFFu + NWPK)         // 9280: packed x follows (256B aligned)

typedef _Float16 h2 __attribute__((ext_vector_type(2)));

// volatile: prevents CSE across the REP diagnostic repeats (each repeat must
// actually execute its 288 mins, or the probe measures nothing).
static __device__ __forceinline__ h2 pkmin_vs(h2 xv, unsigned wu) {
    unsigned xu = __builtin_bit_cast(unsigned, xv);
    unsigned ru;
    asm volatile("v_pk_min_f16 %0, %1, %2" : "=v"(ru) : "v"(xu), "s"(wu));
    return __builtin_bit_cast(h2, ru);
}

// One dispatch, three jobs (fp16 channel-pair packing):
//   blocks [0,841)    : zero-padded x -> fp16 pairs (ch 2cp, 2cp+1) at wsu+XOFFu
//   blocks [841,877)  : weights       -> fp16 pairs at wsu+WOFFu
//   block  877        : mu = mean|w| (fp32) -> ws[0]
__global__ __launch_bounds__(256) void prep(const float* __restrict__ x,
                                            const float* __restrict__ w,
                                            float* __restrict__ ws) {
    unsigned* wsu = reinterpret_cast<unsigned*>(ws);
    if (blockIdx.x < XPKBLKS) {
        int idx = blockIdx.x * 256 + threadIdx.x;      // 0..NXPK-1
        int bc  = idx / PIMG;                          // b*16 + cp
        int r   = idx - bc * PIMG;
        int ph  = r / PW;
        int pw  = r - ph * PW;
        int hh  = ph - 1, wc = pw - 1;
        float v0 = 0.f, v1 = 0.f;
        if ((unsigned)hh < (unsigned)HH && (unsigned)wc < (unsigned)WW) {
            int base = ((bc >> 4) * CIN + (bc & 15) * 2) * IMG + hh * WW + wc;
            v0 = x[base];                              // channel 2cp   (coalesced)
            v1 = x[base + IMG];                        // channel 2cp+1
        }
        h2 p; p.x = (_Float16)v0; p.y = (_Float16)v1;
        wsu[XOFFu + idx] = __builtin_bit_cast(unsigned, p);
        return;
    }
    if (blockIdx.x < XPKBLKS + WPKBLKS) {
        int idx = (blockIdx.x - XPKBLKS) * 256 + threadIdx.x;  // 0..NWPK-1
        int t    = idx % 9;
        int rest = idx / 9;                            // oo*16 + cp
        int cp   = rest & 15;
        int oo   = rest >> 4;
        int base = oo * (CIN * 9) + cp * 18 + t;
        h2 p; p.x = (_Float16)w[base]; p.y = (_Float16)w[base + 9];
        wsu[WOFFu + idx] = __builtin_bit_cast(unsigned, p);
        return;
    }
    // |w| mean (fp32 source) -> ws[0]
    float s = 0.f;
    const float4* w4 = reinterpret_cast<const float4*>(w);
    #pragma unroll
    for (int k = 0; k < 18; ++k) {
        float4 v = w4[k * 256 + threadIdx.x];
        s += fabsf(v.x) + fabsf(v.y) + fabsf(v.z) + fabsf(v.w);
    }
    #pragma unroll
    for (int off = 32; off; off >>= 1) s += __shfl_down(s, off);
    __shared__ float sm[4];
    if ((threadIdx.x & 63) == 0) sm[threadIdx.x >> 6] = s;
    __syncthreads();
    if (threadIdx.x == 0)
        ws[0] = (sm[0] + sm[1] + sm[2] + sm[3]) * (1.0f / (float)NW);
}

// DIAGNOSTIC ROUND (R10): R8 kernel with the compute phase repeated REP=8x
// (results summed, scaled by 1/8 -> numerically exact to ~2e-7).
//   (dur - 70.0)/7 = compute-phase time of minconv.
//   If compute >= ~6us, minconv becomes the TOP dispatch -> first-ever
//   VALUBusy/FETCH counters for it: >65% = issue-bound, <40% = SMEM/latency.
// Loads are NOT repeated (issued once, before the rep loop).
__global__ __launch_bounds__(128) void minconv_kernel(const float* __restrict__ ws,
                                                      const float* __restrict__ wts,
                                                      float* __restrict__ out) {
    const unsigned* wsu = reinterpret_cast<const unsigned*>(ws);
    const int lane = threadIdx.x & 63;
    const int wv   = threadIdx.x >> 6;
    const int wvs  = __builtin_amdgcn_readfirstlane(wv);   // SGPR copy
    const int hw = blockIdx.x * 64 + lane;             // 0..3135 exact
    const int o0 = blockIdx.y * OT;
    const int b  = blockIdx.z;
    const int h  = hw / WW;
    const int w  = hw - h * WW;

    const float mu = ws[0];                            // uniform s_load

    const int cp0 = wvs * 8;                           // this wave's channel-pairs
    const unsigned* xq = wsu + XOFFu + (size_t)(b * 16 + cp0) * PIMG + h * PW + w;
    const unsigned* wq = wsu + WOFFu;                  // scalar-indexed -> s_load

    // ---- phase 1: issue ALL 72 tap loads ONCE ----
    h2 xall[72];                                       // constant-indexed -> VGPRs
    #pragma unroll
    for (int cp = 0; cp < 8; ++cp)
        #pragma unroll
        for (int kh = 0; kh < 3; ++kh)
            #pragma unroll
            for (int kw = 0; kw < 3; ++kw)
                xall[cp * 9 + kh * 3 + kw] =
                    __builtin_bit_cast(h2, xq[cp * PIMG + kh * PW + kw]);

    // ---- phase 2: compute, repeated REP times (diagnostic scaling) ----
    h2 ones; ones.x = (_Float16)1.f; ones.y = (_Float16)1.f;
    float acc0 = 0.f, acc1 = 0.f, acc2 = 0.f, acc3 = 0.f;

    #pragma unroll 1
    for (int rep = 0; rep < REP; ++rep) {
        #pragma unroll
        for (int oo = 0; oo < OT; ++oo) {
            float ae = 0.f, ao = 0.f;                  // even/odd tap chains
            #pragma unroll
            for (int cp = 0; cp < 8; ++cp) {
                const int wbase = ((o0 + oo) * 16 + (cp0 + cp)) * 9;   // scalar
                #pragma unroll
                for (int t = 0; t < 9; ++t) {
                    h2 m = pkmin_vs(xall[cp * 9 + t], wq[wbase + t]);  // v_pk_min_f16
                    if (t & 1) ao = __builtin_amdgcn_fdot2(m, ones, ao, false);
                    else       ae = __builtin_amdgcn_fdot2(m, ones, ae, false);
                }
            }
            float a = ae + ao;
            switch (oo) {                              // literal acc names only
                case 0: acc0 += a; break;
                case 1: acc1 += a; break;
                case 2: acc2 += a; break;
                case 3: acc3 += a; break;
            }
        }
    }

    // cross-wave combine: wave0 keeps oo 0,1; wave1 keeps oo 2,3.
    __shared__ float red[2][2][64];                    // 1 KiB
    if (wv == 0) {
        red[0][0][lane] = acc2;
        red[0][1][lane] = acc3;
    } else {
        red[1][0][lane] = acc0;
        red[1][1][lane] = acc1;
    }
    __syncthreads();

    const float mus = mu * (1.0f / (float)REP);        // undo the REP scaling
    float* ob = out + ((size_t)b * OCH + o0) * IMG + hw;
    if (wv == 0) {
        ob[0]       = mus * (acc0 + red[1][0][lane]);
        ob[IMG]     = mus * (acc1 + red[1][1][lane]);
    } else {
        ob[2 * IMG] = mus * (acc2 + red[0][0][lane]);
        ob[3 * IMG] = mus * (acc3 + red[0][1][lane]);
    }
}

extern "C" void kernel_launch(void* const* d_in, const int* in_sizes, int n_in,
                              void* d_out, int out_size, void* d_ws, size_t ws_size,
                              hipStream_t stream) {
    const float* x   = (const float*)d_in[0];   // 4*32*56*56
    const float* w   = (const float*)d_in[1];   // 64*32*3*3
    float*       out = (float*)d_out;           // 4*64*56*56
    float*       ws  = (float*)d_ws;

    prep<<<XPKBLKS + WPKBLKS + 1, 256, 0, stream>>>(x, w, ws);
    dim3 grid(IMG / 64, OCH / OT, BB);          // 49 x 16 x 4 = 3136 blocks
    minconv_kernel<<<grid, 128, 0, stream>>>(ws, w, out);
}

// Round 11
// 68.604 us; speedup vs baseline: 2.3505x; 2.3505x over previous
//
#include <hip/hip_runtime.h>

#define CIN  32
#define OCH  64
#define HH   56
#define WW   56
#define BB   4
#define OT   4                  // output channels per block
#define IMG  (HH * WW)          // 3136
#define NW   18432              // 64*32*3*3
#define PH   58
#define PW   58
#define PIMG (PH * PW)          // 3364 padded image
#define NXPK (BB * (CIN/2) * PIMG)   // 215296 packed x uints
#define XPKBLKS (NXPK / 256)         // 841 (exact)
#define NWPK (OCH * (CIN/2) * 9)     // 9216 packed weight uints
#define WPKBLKS (NWPK / 256)         // 36 (exact)
#define WOFFu 64                     // packed weights at wsu+64 (uint units)
#define XOFFu (WOFFu + NWPK)         // 9280: packed x follows (256B aligned)

typedef _Float16 h2 __attribute__((ext_vector_type(2)));

// v_pk_min_f16 with the weight as a direct SGPR source (VOP3P allows 1 SGPR
// operand). Non-volatile: scheduler must be free to interleave (R10's
// volatile probe pinned the order; only needed for the REP diagnostic).
static __device__ __forceinline__ h2 pkmin_vs(h2 xv, unsigned wu) {
    unsigned xu = __builtin_bit_cast(unsigned, xv);
    unsigned ru;
    asm("v_pk_min_f16 %0, %1, %2" : "=v"(ru) : "v"(xu), "s"(wu));
    return __builtin_bit_cast(h2, ru);
}

// One dispatch, three jobs (fp16 channel-pair packing):
//   blocks [0,841)    : zero-padded x -> fp16 pairs (ch 2cp, 2cp+1) at wsu+XOFFu
//   blocks [841,877)  : weights       -> fp16 pairs at wsu+WOFFu
//   block  877        : mu = mean|w| (fp32) -> ws[0]
__global__ __launch_bounds__(256) void prep(const float* __restrict__ x,
                                            const float* __restrict__ w,
                                            float* __restrict__ ws) {
    unsigned* wsu = reinterpret_cast<unsigned*>(ws);
    if (blockIdx.x < XPKBLKS) {
        int idx = blockIdx.x * 256 + threadIdx.x;      // 0..NXPK-1
        int bc  = idx / PIMG;                          // b*16 + cp
        int r   = idx - bc * PIMG;
        int ph  = r / PW;
        int pw  = r - ph * PW;
        int hh  = ph - 1, wc = pw - 1;
        float v0 = 0.f, v1 = 0.f;
        if ((unsigned)hh < (unsigned)HH && (unsigned)wc < (unsigned)WW) {
            int base = ((bc >> 4) * CIN + (bc & 15) * 2) * IMG + hh * WW + wc;
            v0 = x[base];                              // channel 2cp   (coalesced)
            v1 = x[base + IMG];                        // channel 2cp+1
        }
        h2 p; p.x = (_Float16)v0; p.y = (_Float16)v1;
        wsu[XOFFu + idx] = __builtin_bit_cast(unsigned, p);
        return;
    }
    if (blockIdx.x < XPKBLKS + WPKBLKS) {
        int idx = (blockIdx.x - XPKBLKS) * 256 + threadIdx.x;  // 0..NWPK-1
        int t    = idx % 9;
        int rest = idx / 9;                            // oo*16 + cp
        int cp   = rest & 15;
        int oo   = rest >> 4;
        int base = oo * (CIN * 9) + cp * 18 + t;
        h2 p; p.x = (_Float16)w[base]; p.y = (_Float16)w[base + 9];
        wsu[WOFFu + idx] = __builtin_bit_cast(unsigned, p);
        return;
    }
    // |w| mean (fp32 source) -> ws[0]
    float s = 0.f;
    const float4* w4 = reinterpret_cast<const float4*>(w);
    #pragma unroll
    for (int k = 0; k < 18; ++k) {
        float4 v = w4[k * 256 + threadIdx.x];
        s += fabsf(v.x) + fabsf(v.y) + fabsf(v.z) + fabsf(v.w);
    }
    #pragma unroll
    for (int off = 32; off; off >>= 1) s += __shfl_down(s, off);
    __shared__ float sm[4];
    if ((threadIdx.x & 63) == 0) sm[threadIdx.x >> 6] = s;
    __syncthreads();
    if (threadIdx.x == 0)
        ws[0] = (sm[0] + sm[1] + sm[2] + sm[3]) * (1.0f / (float)NW);
}

// R10 probe result: compute phase = 13us, VALUBusy 42%, SGPR=32 -> the stall
// is SMEM latency: weights fetched in ~16-dword dribbles, each batch exposing
// ~200cyc against ~50cyc of VALU. Fix: for fixed oo this wave's 72 weight
// dwords are CONTIGUOUS (= (o0+oo)*144 + cp0*9 + [0..71]). Load them as two
// explicit 36-dword uniform half-buffers, software-pipelined: issue the next
// half's loads before consuming the current half -> ~1 lgkm wait per half,
// amortized over 72 VALU ops, with the next batch already in flight.
// R3 lesson: weight addressing stays SGPR-provable (readfirstlane on wv).
// R2 lesson: all register-array indices compile-time.
__global__ __launch_bounds__(128) void minconv_kernel(const float* __restrict__ ws,
                                                      const float* __restrict__ wts,
                                                      float* __restrict__ out) {
    const unsigned* wsu = reinterpret_cast<const unsigned*>(ws);
    const int lane = threadIdx.x & 63;
    const int wv   = threadIdx.x >> 6;
    const int wvs  = __builtin_amdgcn_readfirstlane(wv);   // SGPR copy
    const int hw = blockIdx.x * 64 + lane;             // 0..3135 exact
    const int o0 = blockIdx.y * OT;
    const int b  = blockIdx.z;
    const int h  = hw / WW;
    const int w  = hw - h * WW;

    const float mu = ws[0];                            // uniform s_load

    const int cp0 = wvs * 8;                           // this wave's channel-pairs
    const unsigned* xq = wsu + XOFFu + (size_t)(b * 16 + cp0) * PIMG + h * PW + w;
    // base of this wave's contiguous 72-dword weight block for oo=0
    const unsigned* wq0 = wsu + WOFFu + o0 * 144 + cp0 * 9;

    // ---- phase 1: issue ALL 72 tap loads (VMEM, pipelined) ----
    h2 xall[72];                                       // constant-indexed -> VGPRs
    #pragma unroll
    for (int cp = 0; cp < 8; ++cp)
        #pragma unroll
        for (int kh = 0; kh < 3; ++kh)
            #pragma unroll
            for (int kw = 0; kw < 3; ++kw)
                xall[cp * 9 + kh * 3 + kw] =
                    __builtin_bit_cast(h2, xq[cp * PIMG + kh * PW + kw]);

    // ---- phase 2: compute with software-pipelined 36-dword weight halves ----
    h2 ones; ones.x = (_Float16)1.f; ones.y = (_Float16)1.f;
    float acc0 = 0.f, acc1 = 0.f, acc2 = 0.f, acc3 = 0.f;

    unsigned wA[36], wB[36];                           // uniform -> SGPR batches
    #pragma unroll
    for (int i = 0; i < 36; ++i) wA[i] = wq0[i];       // prefetch oo=0 half A

    #pragma unroll
    for (int oo = 0; oo < OT; ++oo) {
        // issue half B loads (cp 4..7 of this oo) before consuming half A
        #pragma unroll
        for (int i = 0; i < 36; ++i) wB[i] = wq0[oo * 144 + 36 + i];

        float ae = 0.f, ao = 0.f;                      // even/odd tap chains
        #pragma unroll
        for (int cp = 0; cp < 4; ++cp)                 // half A: cp 0..3
            #pragma unroll
            for (int t = 0; t < 9; ++t) {
                h2 m = pkmin_vs(xall[cp * 9 + t], wA[cp * 9 + t]);
                if (t & 1) ao = __builtin_amdgcn_fdot2(m, ones, ao, false);
                else       ae = __builtin_amdgcn_fdot2(m, ones, ae, false);
            }

        // issue next oo's half A loads before consuming half B
        if (oo < OT - 1) {
            #pragma unroll
            for (int i = 0; i < 36; ++i) wA[i] = wq0[(oo + 1) * 144 + i];
        }

        #pragma unroll
        for (int cp = 0; cp < 4; ++cp)                 // half B: cp 4..7
            #pragma unroll
            for (int t = 0; t < 9; ++t) {
                h2 m = pkmin_vs(xall[(cp + 4) * 9 + t], wB[cp * 9 + t]);
                if (t & 1) ao = __builtin_amdgcn_fdot2(m, ones, ao, false);
                else       ae = __builtin_amdgcn_fdot2(m, ones, ae, false);
            }

        float a = ae + ao;
        switch (oo) {                                  // literal acc names only
            case 0: acc0 = a; break;
            case 1: acc1 = a; break;
            case 2: acc2 = a; break;
            case 3: acc3 = a; break;
        }
    }

    // cross-wave combine: wave0 keeps oo 0,1; wave1 keeps oo 2,3.
    __shared__ float red[2][2][64];                    // 1 KiB
    if (wv == 0) {
        red[0][0][lane] = acc2;
        red[0][1][lane] = acc3;
    } else {
        red[1][0][lane] = acc0;
        red[1][1][lane] = acc1;
    }
    __syncthreads();

    float* ob = out + ((size_t)b * OCH + o0) * IMG + hw;
    if (wv == 0) {
        ob[0]       = mu * (acc0 + red[1][0][lane]);
        ob[IMG]     = mu * (acc1 + red[1][1][lane]);
    } else {
        ob[2 * IMG] = mu * (acc2 + red[0][0][lane]);
        ob[3 * IMG] = mu * (acc3 + red[0][1][lane]);
    }
}

extern "C" void kernel_launch(void* const* d_in, const int* in_sizes, int n_in,
                              void* d_out, int out_size, void* d_ws, size_t ws_size,
                              hipStream_t stream) {
    const float* x   = (const float*)d_in[0];   // 4*32*56*56
    const float* w   = (const float*)d_in[1];   // 64*32*3*3
    float*       out = (float*)d_out;           // 4*64*56*56
    float*       ws  = (float*)d_ws;

    prep<<<XPKBLKS + WPKBLKS + 1, 256, 0, stream>>>(x, w, ws);
    dim3 grid(IMG / 64, OCH / OT, BB);          // 49 x 16 x 4 = 3136 blocks
    minconv_kernel<<<grid, 128, 0, stream>>>(ws, w, out);
}